// Round 1
// 3563.992 us; speedup vs baseline: 1.0613x; 1.0613x over previous
//
#include <hip/hip_runtime.h>

#define DEV __device__ __forceinline__

#define B_    16
#define T_    100
#define S_    400
#define V_    50000
#define EXTV  51000
#define E_    128
#define H_    256
#define H4_   1024
#define NEG_  (-1e12f)
#define NWG_  80

DEV unsigned short f2bf(float x) {            // RNE float->bf16 bits
    unsigned int u = __float_as_uint(x);
    u = (u + 0x7FFFu + ((u >> 16) & 1u)) >> 16;
    return (unsigned short)u;
}
DEV float sigm(float x) { return 1.f / (1.f + __expf(-x)); }

// Device-scope grid barrier (cnt/gen in separate cachelines).
// All NWG_ WGs co-resident by construction (80 WGs << 256 CUs).
DEV void gbar(unsigned int* cnt, unsigned int* gen) {
    __syncthreads();
    if (threadIdx.x == 0) {
        __threadfence();   // release: wbl2 -> my XCD's dirty lines to L3
        unsigned int g = __hip_atomic_load(gen, __ATOMIC_RELAXED, __HIP_MEMORY_SCOPE_AGENT);
        if (__hip_atomic_fetch_add(cnt, 1u, __ATOMIC_ACQ_REL, __HIP_MEMORY_SCOPE_AGENT) == NWG_ - 1u) {
            __hip_atomic_store(cnt, 0u, __ATOMIC_RELAXED, __HIP_MEMORY_SCOPE_AGENT);
            __hip_atomic_store(gen, g + 1u, __ATOMIC_RELEASE, __HIP_MEMORY_SCOPE_AGENT);
        } else {
            while (__hip_atomic_load(gen, __ATOMIC_RELAXED, __HIP_MEMORY_SCOPE_AGENT) == g) {
                __builtin_amdgcn_s_sleep(1);
            }
        }
        __threadfence();   // acquire: inv L1/L2 so we see remote writes
    }
    __syncthreads();
}

__global__ void k_init(unsigned int* bar) { bar[0] = 0u; bar[64] = 0u; }

// ---------------- prep kernels ----------------

// memories[b,s,:] = enc[b,s,:] @ W_enc + b_enc   (16 rows per block)
__global__ void k_mem(const float* __restrict__ enc, const float* __restrict__ W_enc,
                      const float* __restrict__ b_enc, float* __restrict__ mem) {
    __shared__ float u[16][H_];
    int base = blockIdx.x * 16;          // 400 blocks, 6400 rows
    int j = threadIdx.x;                 // 256
    for (int r = 0; r < 16; ++r) u[r][j] = enc[(base + r) * H_ + j];
    __syncthreads();
    float acc[16];
    float bb = b_enc[j];
    for (int r = 0; r < 16; ++r) acc[r] = bb;
    for (int k = 0; k < H_; ++k) {
        float wv = W_enc[k * H_ + j];
        for (int r = 0; r < 16; ++r) acc[r] = fmaf(u[r][k], wv, acc[r]);
    }
    for (int r = 0; r < 16; ++r) mem[(base + r) * H_ + j] = acc[r];
}

// Kt[col][k] (1024 x 512), WtW = W_red_top @ Wx (128x1024), bvec = b_red@Wx + b_lstm
__global__ void k_prepw(const float* __restrict__ W_red, const float* __restrict__ Wx,
                        const float* __restrict__ Wh, const float* __restrict__ b_red,
                        const float* __restrict__ b_lstm,
                        float* __restrict__ Kt, float* __restrict__ WtW, float* __restrict__ bvec) {
    int c = blockIdx.x * 256 + threadIdx.x;   // 0..1023
    int r = blockIdx.y;                       // 0..640
    if (r < 384) {
        float acc = 0.f;
        for (int j = 0; j < E_; ++j) acc = fmaf(W_red[r * E_ + j], Wx[j * H4_ + c], acc);
        if (r < 128) WtW[r * H4_ + c] = acc;
        else         Kt[c * 512 + (r - 128)] = acc;        // ctx rows 0..255
    } else if (r < 640) {
        Kt[c * 512 + 256 + (r - 384)] = Wh[(r - 384) * H4_ + c];  // h rows 256..511
    } else {
        float acc = b_lstm[c];
        for (int j = 0; j < E_; ++j) acc = fmaf(b_red[j], Wx[j * H4_ + c], acc);
        bvec[c] = acc;
    }
}

// Zpre[(t*16+b), :] = emb[y(b,t)] @ WtW + bvec    grid (100, 4)
__global__ void k_zpre(const int* __restrict__ trg, const float* __restrict__ emb,
                       const float* __restrict__ WtW, const float* __restrict__ bvec,
                       float* __restrict__ Zpre) {
    __shared__ float u[16][E_];
    int t = blockIdx.x, q = blockIdx.y;
    int tid = threadIdx.x;                    // 256
    for (int idx = tid; idx < 16 * E_; idx += 256) {
        int b = idx >> 7, k = idx & 127;
        u[b][k] = emb[trg[b * T_ + t] * E_ + k];
    }
    __syncthreads();
    int c = q * 256 + tid;
    float acc[16];
    float bv = bvec[c];
    for (int b = 0; b < 16; ++b) acc[b] = bv;
    for (int k = 0; k < E_; ++k) {
        float wv = WtW[k * H4_ + c];
        for (int b = 0; b < 16; ++b) acc[b] = fmaf(u[b][k], wv, acc[b]);
    }
    for (int b = 0; b < 16; ++b) Zpre[(t * 16 + b) * H4_ + c] = acc[b];
}

// ---------------- persistent decode loop ----------------
// 80 WGs x 512 threads, all co-resident. Per step:
//   phase A (WGs 0..63): merge ctx_{t-1} from 5 chunk partials, z = Zpre + [ctx,h]@K
//                        (K held in LDS for all 100 steps), gates (c state in regs),
//                        write ws_h[t].
//   grid barrier
//   phase B (all 80 WGs = batch x s-chunk): masked energy -> ws_en, chunk softmax
//                        partials (Mpart,Zpart) and ctx partial (Cpart).
//   grid barrier
__global__ void __launch_bounds__(512) k_loop(
    const float* __restrict__ Kt, const float* __restrict__ Zpre,
    const float* __restrict__ init_h, const float* __restrict__ init_c,
    const float* __restrict__ memw, const int* __restrict__ enc_mask,
    float* __restrict__ Mpart, float* __restrict__ Zpart, float* __restrict__ Cpart,
    float* __restrict__ ws_h, float* __restrict__ ws_ctx, float* __restrict__ ws_en,
    unsigned int* bar) {
    __shared__ __align__(16) float Kl[16 * 512];   // persistent K columns (A-WGs)
    __shared__ __align__(16) float vL[16 * 512];   // [b][k]: k<256 ctx, k>=256 h
    __shared__ float zscr[16 * 17];
    __shared__ float swL[80];
    __shared__ float invd[16];
    __shared__ float hA[H_];
    __shared__ float eL[80];
    __shared__ float pL[80];
    __shared__ float red1[1];
    __shared__ float cL[512];

    const int w = blockIdx.x, tid = threadIdx.x;
    const int ub = (w & 63) << 2;                  // 4 hidden units per A-WG

    // persistent LSTM cell state: thread (tid<64, w<64) owns c[(tid&15)][ub+(tid>>4)]
    float c_state = 0.f;
    if (w < 64 && tid < 64)
        c_state = init_c[(tid & 15) * H_ + ub + (tid >> 4)];

    // stage this WG's 16 K-columns into LDS once (reused for all 100 steps)
    if (w < 64) {
        for (int idx = tid; idx < 16 * 512; idx += 512) {
            int cs = idx >> 9, k = idx & 511;
            int col = ((cs >> 2) << 8) + ub + (cs & 3);
            Kl[idx] = Kt[col * 512 + k];
        }
    }

    unsigned int* cnt = bar;
    unsigned int* gen = bar + 64;

    for (int t = 0; ; ++t) {
        // ---- phase A: merge ctx_{t-1} + h_{t-1} into vL ----
        const bool aw = (t == T_) ? (w < 16) : (w < 64);
        if (aw) {
            if (t == 0) {
                for (int idx = tid; idx < 4096; idx += 512) {
                    int b = idx >> 8, k = idx & 255;
                    vL[b * 512 + k] = 0.f;                          // ctx_{-1} = 0
                    vL[b * 512 + 256 + k] = init_h[b * H_ + k];     // h_{-1}
                }
            } else {
                if (tid < 16) {
                    int b = tid;
                    float m[5], zp[5];
                    float M = -3.0e38f;
                    for (int i = 0; i < 5; ++i) {
                        m[i] = Mpart[i * 16 + b]; zp[i] = Zpart[i * 16 + b];
                        M = fmaxf(M, m[i]);
                    }
                    float den = 0.f;
                    for (int i = 0; i < 5; ++i) {
                        float s = __expf(m[i] - M);
                        swL[i * 16 + b] = s;
                        den = fmaf(zp[i], s, den);
                    }
                    invd[b] = 1.f / den;
                }
                __syncthreads();
                for (int idx = tid; idx < 4096; idx += 512) {
                    int b = idx >> 8, k = idx & 255;
                    float v = 0.f;
                    for (int i = 0; i < 5; ++i)
                        v = fmaf(Cpart[(i * 16 + b) * H_ + k], swL[i * 16 + b], v);
                    v *= invd[b];
                    vL[b * 512 + k] = v;
                    if (w == b) ws_ctx[((t - 1) * 16 + b) * H_ + k] = v;   // record ctx_{t-1}
                    vL[b * 512 + 256 + k] = ws_h[((t - 1) * 16 + b) * H_ + k];
                }
            }
        }
        if (t == T_) break;

        // ---- z = [ctx,h] @ K, gates ----
        if (w < 64) {
            __syncthreads();
            const int wv = tid >> 6, kl = tid & 63, k0 = kl << 3;
            for (int pass = 0; pass < 2; ++pass) {
                const int cs = pass * 8 + wv;       // cs = gate*4 + unit_offset
                const float4 kv0 = *(const float4*)(Kl + cs * 512 + k0);
                const float4 kv1 = *(const float4*)(Kl + cs * 512 + k0 + 4);
                for (int b = 0; b < 16; ++b) {
                    float4 v0 = *(const float4*)(vL + b * 512 + k0);
                    float4 v1 = *(const float4*)(vL + b * 512 + k0 + 4);
                    float acc = v0.x * kv0.x;
                    acc = fmaf(v0.y, kv0.y, acc); acc = fmaf(v0.z, kv0.z, acc);
                    acc = fmaf(v0.w, kv0.w, acc); acc = fmaf(v1.x, kv1.x, acc);
                    acc = fmaf(v1.y, kv1.y, acc); acc = fmaf(v1.z, kv1.z, acc);
                    acc = fmaf(v1.w, kv1.w, acc);
                    for (int off = 32; off; off >>= 1) acc += __shfl_xor(acc, off);
                    if (kl == 0) zscr[cs * 17 + b] = acc;
                }
            }
            __syncthreads();
            if (tid < 64) {                         // gates (keras order i,f,g,o)
                const int gu = tid >> 4, gb = tid & 15;
                const float* zp2 = Zpre + (t * 16 + gb) * H4_;
                float zi = zscr[gu * 17 + gb]        + zp2[ub + gu];
                float zf = zscr[(4 + gu) * 17 + gb]  + zp2[256 + ub + gu];
                float zg = zscr[(8 + gu) * 17 + gb]  + zp2[512 + ub + gu];
                float zo = zscr[(12 + gu) * 17 + gb] + zp2[768 + ub + gu];
                float cn = sigm(zf) * c_state + sigm(zi) * tanhf(zg);
                c_state = cn;
                ws_h[(t * 16 + gb) * H_ + ub + gu] = sigm(zo) * tanhf(cn);
            }
        }
        gbar(cnt, gen);

        // ---- phase B: attention partials (all 80 WGs) ----
        {
            const int bw = w & 15, sg = w >> 4;
            if (tid < H_) hA[tid] = ws_h[(t * 16 + bw) * H_ + tid];
            __syncthreads();
            if (tid < 320) {                        // 4 lanes per s-row
                const int s = tid >> 2, kq = tid & 3;
                const float* mrow = memw + (bw * S_ + sg * 80 + s) * H_ + (kq << 6);
                const float* ha = hA + (kq << 6);
                float e = 0.f;
                for (int k = 0; k < 64; k += 4) {
                    float4 mm = *(const float4*)(mrow + k);
                    e = fmaf(ha[k], mm.x, e);     e = fmaf(ha[k + 1], mm.y, e);
                    e = fmaf(ha[k + 2], mm.z, e); e = fmaf(ha[k + 3], mm.w, e);
                }
                e += __shfl_xor(e, 1);
                e += __shfl_xor(e, 2);
                if (kq == 0) {
                    if (enc_mask[bw * S_ + sg * 80 + s] == 0) e = NEG_;
                    ws_en[(t * 16 + bw) * S_ + sg * 80 + s] = e;   // masked energy = copy score
                    eL[s] = e;
                }
            }
            __syncthreads();
            if (tid < 64) {
                float m = eL[tid];
                if (tid < 16) m = fmaxf(m, eL[64 + tid]);
                for (int off = 32; off; off >>= 1) m = fmaxf(m, __shfl_down(m, off));
                if (tid == 0) red1[0] = m;
            }
            __syncthreads();
            const float mw = red1[0];
            if (tid < 80) pL[tid] = __expf(eL[tid] - mw);
            __syncthreads();
            if (tid < 64) {
                float zz = pL[tid] + ((tid < 16) ? pL[64 + tid] : 0.f);
                for (int off = 32; off; off >>= 1) zz += __shfl_down(zz, off);
                if (tid == 0) { Mpart[sg * 16 + bw] = mw; Zpart[sg * 16 + bw] = zz; }
            }
            {   // ctx partial: k = tid&255, s-halves of 40 summed across tid>>8
                const int k = tid & 255, half = tid >> 8;
                float acc = 0.f;
                const float* mbase = memw + (bw * S_ + sg * 80) * H_;
                for (int s = half * 40; s < half * 40 + 40; ++s)
                    acc = fmaf(pL[s], mbase[s * H_ + k], acc);
                cL[tid] = acc;
                __syncthreads();
                if (tid < 256) Cpart[(sg * 16 + bw) * H_ + tid] = cL[tid] + cL[tid + 256];
            }
        }
        gbar(cnt, gen);
    }
}

// ---------------- epilogue kernels ----------------

// a[tb] = tanh([h,ctx] @ W_cat + b_cat) -> bf16
__global__ void k_precat(const float* __restrict__ ws_h, const float* __restrict__ ws_ctx,
                         const float* __restrict__ W_cat, const float* __restrict__ b_cat,
                         unsigned short* __restrict__ Abf) {
    __shared__ float u[16][512];
    int base = blockIdx.x * 16;     // 104 blocks (pad rows 1600..1663 -> 0)
    int tid = threadIdx.x;          // 256
    for (int idx = tid; idx < 16 * 512; idx += 256) {
        int r = idx >> 9, k = idx & 511;
        int row = base + r;
        float v = 0.f;
        if (row < 1600) v = (k < 256) ? ws_h[row * H_ + k] : ws_ctx[row * H_ + (k - 256)];
        u[r][k] = v;
    }
    __syncthreads();
    float acc[16];
    float bc = b_cat[tid];
    for (int r = 0; r < 16; ++r) acc[r] = bc;
    for (int k = 0; k < 512; ++k) {
        float wv = W_cat[k * H_ + tid];
        for (int r = 0; r < 16; ++r) acc[r] = fmaf(u[r][k], wv, acc[r]);
    }
    for (int r = 0; r < 16; ++r) {
        int row = base + r;
        float a = (row < 1600) ? tanhf(acc[r]) : 0.f;
        Abf[row * H_ + tid] = f2bf(a);
    }
}

// W_out [256][50000] fp32 -> Bt [51072][256] bf16 (transposed, zero-padded), bias_pad
__global__ void k_convw(const float* __restrict__ Wout, const float* __restrict__ bout,
                        unsigned short* __restrict__ Bt, float* __restrict__ biasp) {
    __shared__ float tile[64][65];
    int bx = blockIdx.x;   // 0..797
    int by = blockIdx.y;   // 0..3
    int tid = threadIdx.x; // 256
    int tr = tid >> 6, tc = tid & 63;
    for (int i = 0; i < 16; ++i) {
        int k = by * 64 + tr + i * 4;
        int n = bx * 64 + tc;
        tile[tr + i * 4][tc] = (n < V_) ? Wout[k * V_ + n] : 0.f;
    }
    __syncthreads();
    for (int i = 0; i < 16; ++i) {
        int nl = tr + i * 4;
        int n = bx * 64 + nl;
        int k = by * 64 + tc;
        Bt[n * 256 + k] = f2bf(tile[tc][nl]);
    }
    if (by == 0 && tid < 64) {
        int n = bx * 64 + tid;
        biasp[n] = (n < V_) ? bout[n] : 0.f;
    }
}

typedef __attribute__((ext_vector_type(8))) __bf16 bf16x8;
typedef __attribute__((ext_vector_type(4))) float f32x4;

// out[b,t,:] = A[tb] @ W_out^T(bf16) + bias   M=1600(pad 1664) N=51072(guard 51000) K=256
__global__ void __launch_bounds__(256) k_gemm(
    const unsigned short* __restrict__ A, const unsigned short* __restrict__ Bt,
    const float* __restrict__ biasp, float* __restrict__ out) {
    __shared__ __align__(16) unsigned short As[128 * 64];
    __shared__ __align__(16) unsigned short Bs[128 * 64];
    const int nb = blockIdx.x, mb = blockIdx.y;
    const int tid = threadIdx.x;
    const int lane = tid & 63, wv = tid >> 6;
    const int wm = wv >> 1, wn = wv & 1;
    const int q = lane >> 4, r16 = lane & 15;
    f32x4 acc[4][4];
    for (int i = 0; i < 4; ++i) for (int j = 0; j < 4; ++j) acc[i][j] = (f32x4)0.f;
    for (int kb = 0; kb < 4; ++kb) {
        for (int i = 0; i < 4; ++i) {   // stage 128x64 A and B tiles, XOR-swizzled rows
            int idx = tid + (i << 8);
            int m = idx >> 3, c = idx & 7;
            int sl = ((c ^ (m & 7)) << 3);
            *(uint4*)(As + (m << 6) + sl) = *(const uint4*)(A + (mb * 128 + m) * 256 + (kb << 6) + (c << 3));
            *(uint4*)(Bs + (m << 6) + sl) = *(const uint4*)(Bt + (nb * 128 + m) * 256 + (kb << 6) + (c << 3));
        }
        __syncthreads();
        for (int k32 = 0; k32 < 2; ++k32) {
            bf16x8 af[4], bfr[4];
            int c = (k32 << 2) + q;
            for (int mt = 0; mt < 4; ++mt) {
                int m = wm * 64 + mt * 16 + r16;
                af[mt] = *(const bf16x8*)(As + (m << 6) + ((c ^ (m & 7)) << 3));
            }
            for (int nt = 0; nt < 4; ++nt) {
                int n = wn * 64 + nt * 16 + r16;
                bfr[nt] = *(const bf16x8*)(Bs + (n << 6) + ((c ^ (n & 7)) << 3));
            }
            for (int mt = 0; mt < 4; ++mt)
                for (int nt = 0; nt < 4; ++nt)
                    acc[mt][nt] = __builtin_amdgcn_mfma_f32_16x16x32_bf16(af[mt], bfr[nt], acc[mt][nt], 0, 0, 0);
        }
        __syncthreads();
    }
    for (int nt = 0; nt < 4; ++nt) {
        int col = nb * 128 + wn * 64 + nt * 16 + r16;
        if (col >= EXTV) continue;
        float bs = biasp[col];
        for (int mt = 0; mt < 4; ++mt) {
            int rbase = mb * 128 + wm * 64 + mt * 16 + (q << 2);
            for (int rg = 0; rg < 4; ++rg) {
                int row = rbase + rg;
                if (row < 1600) {
                    int tt = row >> 4, bb = row & 15;
                    out[(bb * T_ + tt) * EXTV + col] = acc[mt][nt][rg] + bs;
                }
            }
        }
    }
}

// pointer-generator copy scores: per (b,t) scatter-max of masked energy, += into out
__global__ void k_scatter(const int* __restrict__ ext_ids, const float* __restrict__ ws_en,
                          float* __restrict__ out) {
    __shared__ int ids[S_];
    __shared__ float en[S_];
    int r = blockIdx.x;           // t*16+b
    int t = r >> 4, b = r & 15;
    int tid = threadIdx.x;        // 256
    for (int s = tid; s < S_; s += 256) {
        ids[s] = ext_ids[b * S_ + s];
        en[s] = ws_en[r * S_ + s];
    }
    __syncthreads();
    for (int s = tid; s < S_; s += 256) {
        int id = ids[s];
        float mx = en[s];
        int fo = s;
        for (int s2 = 0; s2 < S_; ++s2) {
            if (ids[s2] == id) { mx = fmaxf(mx, en[s2]); if (s2 < fo) fo = s2; }
        }
        if (fo == s && mx >= NEG_ * 0.5f)
            out[(b * T_ + t) * EXTV + id] += mx;
    }
}

// ---------------- launch ----------------

extern "C" void kernel_launch(void* const* d_in, const int* in_sizes, int n_in,
                              void* d_out, int out_size, void* d_ws, size_t ws_size,
                              hipStream_t stream) {
    (void)in_sizes; (void)n_in; (void)out_size; (void)ws_size;
    const int*   trg     = (const int*)d_in[0];
    const int*   ext_ids = (const int*)d_in[1];
    const int*   mask    = (const int*)d_in[2];
    const float* enc     = (const float*)d_in[3];
    const float* init_h  = (const float*)d_in[4];
    const float* init_c  = (const float*)d_in[5];
    const float* emb     = (const float*)d_in[6];
    const float* W_enc   = (const float*)d_in[7];
    const float* b_enc   = (const float*)d_in[8];
    const float* W_red   = (const float*)d_in[9];
    const float* b_red   = (const float*)d_in[10];
    const float* Wx      = (const float*)d_in[11];
    const float* Wh      = (const float*)d_in[12];
    const float* b_lstm  = (const float*)d_in[13];
    const float* W_cat   = (const float*)d_in[14];
    const float* b_cat   = (const float*)d_in[15];
    const float* W_out   = (const float*)d_in[16];
    const float* b_out   = (const float*)d_in[17];
    float* out = (float*)d_out;

    char* p = (char*)d_ws;
    auto alloc = [&](size_t bytes) { char* r = p; p += ((bytes + 255) & ~size_t(255)); return r; };
    float* mem_w = (float*)alloc(1638400u * 4);    // [16][400][256]
    float* Kt    = (float*)alloc(524288u * 4);     // [1024][512]
    float* WtW   = (float*)alloc(131072u * 4);     // [128][1024]
    float* bvec  = (float*)alloc(1024u * 4);
    float* Zpre  = (float*)alloc(1638400u * 4);    // [1600][1024]
    float* Mpart = (float*)alloc(128u * 4);
    float* Zpart = (float*)alloc(128u * 4);
    float* Cpart = (float*)alloc(20480u * 4);      // [5][16][256]
    float* ws_h  = (float*)alloc(409600u * 4);     // [1600][256]
    float* ws_ctx= (float*)alloc(409600u * 4);
    float* ws_en = (float*)alloc(640000u * 4);     // [1600][400]
    unsigned short* Abf = (unsigned short*)alloc(425984u * 2);     // [1664][256] bf16
    unsigned short* Bt  = (unsigned short*)alloc(13074432u * 2);   // [51072][256] bf16
    float* biasp = (float*)alloc(51072u * 4);
    unsigned int* bar = (unsigned int*)alloc(256u * 4);            // barrier cnt/gen

    k_init<<<dim3(1), dim3(1), 0, stream>>>(bar);
    k_mem<<<dim3(400), dim3(256), 0, stream>>>(enc, W_enc, b_enc, mem_w);
    k_prepw<<<dim3(4, 641), dim3(256), 0, stream>>>(W_red, Wx, Wh, b_red, b_lstm, Kt, WtW, bvec);
    k_zpre<<<dim3(100, 4), dim3(256), 0, stream>>>(trg, emb, WtW, bvec, Zpre);

    k_loop<<<dim3(NWG_), dim3(512), 0, stream>>>(Kt, Zpre, init_h, init_c, mem_w, mask,
                                                 Mpart, Zpart, Cpart, ws_h, ws_ctx, ws_en, bar);

    k_precat<<<dim3(104), dim3(256), 0, stream>>>(ws_h, ws_ctx, W_cat, b_cat, Abf);
    k_convw<<<dim3(798, 4), dim3(256), 0, stream>>>(W_out, b_out, Bt, biasp);
    k_gemm<<<dim3(399, 13), dim3(256), 0, stream>>>(Abf, Bt, biasp, out);
    k_scatter<<<dim3(1600), dim3(256), 0, stream>>>(ext_ids, ws_en, out);
}

// Round 2
// 2774.082 us; speedup vs baseline: 1.3635x; 1.2847x over previous
//
#include <hip/hip_runtime.h>

#define DEV __device__ __forceinline__

#define B_    16
#define T_    100
#define S_    400
#define V_    50000
#define EXTV  51000
#define E_    128
#define H_    256
#define H4_   1024
#define NEG_  (-1e12f)
#define NWG_  80

DEV unsigned short f2bf(float x) {            // RNE float->bf16 bits
    unsigned int u = __float_as_uint(x);
    u = (u + 0x7FFFu + ((u >> 16) & 1u)) >> 16;
    return (unsigned short)u;
}
DEV float sigm(float x) { return 1.f / (1.f + __expf(-x)); }

// ---- device-coherent (sc1) scalar access: cross-WG mailbox data only ----
DEV float aload(const float* p) {
    return __uint_as_float(__hip_atomic_load((const unsigned int*)p,
                           __ATOMIC_RELAXED, __HIP_MEMORY_SCOPE_AGENT));
}
DEV void astore(float* p, float v) {
    __hip_atomic_store((unsigned int*)p, __float_as_uint(v),
                       __ATOMIC_RELAXED, __HIP_MEMORY_SCOPE_AGENT);
}

// Fenceless grid barrier. Correctness: __syncthreads() drains vmcnt(0) for every
// wave, and all cross-WG data moves via sc1 (agent-scope) ops whose retirement is
// device-wide visibility — so no buffer_wbl2/buffer_inv is needed and L2 stays warm.
// flags are cacheline-padded (stride 16 ints); tokens increase monotonically.
DEV void gbar(int* bar, int token) {
    __syncthreads();                               // all waves' stores retired
    const int tid = threadIdx.x;
    int* gen = bar + 1344;
    if (blockIdx.x == 0) {
        if (tid >= 1 && tid < NWG_) {              // 79 parallel pollers
            while (__hip_atomic_load(bar + tid * 16, __ATOMIC_RELAXED,
                                     __HIP_MEMORY_SCOPE_AGENT) < token)
                __builtin_amdgcn_s_sleep(2);
        }
        __syncthreads();
        if (tid == 0)
            __hip_atomic_store(gen, token, __ATOMIC_RELAXED, __HIP_MEMORY_SCOPE_AGENT);
    } else {
        if (tid == 0) {
            __hip_atomic_store(bar + blockIdx.x * 16, token,
                               __ATOMIC_RELAXED, __HIP_MEMORY_SCOPE_AGENT);
            while (__hip_atomic_load(gen, __ATOMIC_RELAXED,
                                     __HIP_MEMORY_SCOPE_AGENT) < token)
                __builtin_amdgcn_s_sleep(2);
        }
        __syncthreads();
    }
}

__global__ void k_init(int* bar) {
    for (int i = threadIdx.x; i < 2048; i += 256) bar[i] = 0;
}

// ---------------- prep kernels ----------------

// memories[b,s,:] = enc[b,s,:] @ W_enc + b_enc   (16 rows per block)
__global__ void k_mem(const float* __restrict__ enc, const float* __restrict__ W_enc,
                      const float* __restrict__ b_enc, float* __restrict__ mem) {
    __shared__ float u[16][H_];
    int base = blockIdx.x * 16;          // 400 blocks, 6400 rows
    int j = threadIdx.x;                 // 256
    for (int r = 0; r < 16; ++r) u[r][j] = enc[(base + r) * H_ + j];
    __syncthreads();
    float acc[16];
    float bb = b_enc[j];
    for (int r = 0; r < 16; ++r) acc[r] = bb;
    for (int k = 0; k < H_; ++k) {
        float wv = W_enc[k * H_ + j];
        for (int r = 0; r < 16; ++r) acc[r] = fmaf(u[r][k], wv, acc[r]);
    }
    for (int r = 0; r < 16; ++r) mem[(base + r) * H_ + j] = acc[r];
}

// Kt[col][k] (1024 x 512), WtW = W_red_top @ Wx (128x1024), bvec = b_red@Wx + b_lstm
__global__ void k_prepw(const float* __restrict__ W_red, const float* __restrict__ Wx,
                        const float* __restrict__ Wh, const float* __restrict__ b_red,
                        const float* __restrict__ b_lstm,
                        float* __restrict__ Kt, float* __restrict__ WtW, float* __restrict__ bvec) {
    int c = blockIdx.x * 256 + threadIdx.x;   // 0..1023
    int r = blockIdx.y;                       // 0..640
    if (r < 384) {
        float acc = 0.f;
        for (int j = 0; j < E_; ++j) acc = fmaf(W_red[r * E_ + j], Wx[j * H4_ + c], acc);
        if (r < 128) WtW[r * H4_ + c] = acc;
        else         Kt[c * 512 + (r - 128)] = acc;        // ctx rows 0..255
    } else if (r < 640) {
        Kt[c * 512 + 256 + (r - 384)] = Wh[(r - 384) * H4_ + c];  // h rows 256..511
    } else {
        float acc = b_lstm[c];
        for (int j = 0; j < E_; ++j) acc = fmaf(b_red[j], Wx[j * H4_ + c], acc);
        bvec[c] = acc;
    }
}

// Zpre[(t*16+b), :] = emb[y(b,t)] @ WtW + bvec    grid (100, 4)
__global__ void k_zpre(const int* __restrict__ trg, const float* __restrict__ emb,
                       const float* __restrict__ WtW, const float* __restrict__ bvec,
                       float* __restrict__ Zpre) {
    __shared__ float u[16][E_];
    int t = blockIdx.x, q = blockIdx.y;
    int tid = threadIdx.x;                    // 256
    for (int idx = tid; idx < 16 * E_; idx += 256) {
        int b = idx >> 7, k = idx & 127;
        u[b][k] = emb[trg[b * T_ + t] * E_ + k];
    }
    __syncthreads();
    int c = q * 256 + tid;
    float acc[16];
    float bv = bvec[c];
    for (int b = 0; b < 16; ++b) acc[b] = bv;
    for (int k = 0; k < E_; ++k) {
        float wv = WtW[k * H4_ + c];
        for (int b = 0; b < 16; ++b) acc[b] = fmaf(u[b][k], wv, acc[b]);
    }
    for (int b = 0; b < 16; ++b) Zpre[(t * 16 + b) * H4_ + c] = acc[b];
}

// ---------------- persistent decode loop ----------------
// 80 WGs x 512 threads, all co-resident. Cross-WG traffic (ws_h row, Mpart/Zpart/
// Cpart) goes through sc1 atomics; everything else stays L2-cached across steps.
__global__ void __launch_bounds__(512) k_loop(
    const float* __restrict__ Kt, const float* __restrict__ Zpre,
    const float* __restrict__ init_h, const float* __restrict__ init_c,
    const float* __restrict__ memw, const int* __restrict__ enc_mask,
    float* __restrict__ Mpart, float* __restrict__ Zpart, float* __restrict__ Cpart,
    float* __restrict__ ws_h, float* __restrict__ ws_ctx, float* __restrict__ ws_en,
    int* bar) {
    __shared__ __align__(16) float Kl[16 * 512];   // persistent K columns (A-WGs)
    __shared__ __align__(16) float vL[16 * 512];   // [b][k]: k<256 ctx, k>=256 h
    __shared__ float zscr[16 * 17];
    __shared__ float swL[80];
    __shared__ float invd[16];
    __shared__ float hA[H_];
    __shared__ float eL[80];
    __shared__ float pL[80];
    __shared__ float red1[1];
    __shared__ float cL[512];

    const int w = blockIdx.x, tid = threadIdx.x;
    const int ub = (w & 63) << 2;                  // 4 hidden units per A-WG

    // persistent LSTM cell state: thread (tid<64, w<64) owns c[(tid&15)][ub+(tid>>4)]
    float c_state = 0.f;
    if (w < 64 && tid < 64)
        c_state = init_c[(tid & 15) * H_ + ub + (tid >> 4)];

    // stage this WG's 16 K-columns into LDS once (reused for all 100 steps)
    if (w < 64) {
        for (int idx = tid; idx < 16 * 512; idx += 512) {
            int cs = idx >> 9, k = idx & 511;
            int col = ((cs >> 2) << 8) + ub + (cs & 3);
            Kl[idx] = Kt[col * 512 + k];
        }
    }

    for (int t = 0; ; ++t) {
        // ---- phase A: merge ctx_{t-1} + h_{t-1} into vL ----
        const bool aw = (t == T_) ? (w < 16) : (w < 64);
        if (aw) {
            if (t == 0) {
                for (int idx = tid; idx < 4096; idx += 512) {
                    int b = idx >> 8, k = idx & 255;
                    vL[b * 512 + k] = 0.f;                          // ctx_{-1} = 0
                    vL[b * 512 + 256 + k] = init_h[b * H_ + k];     // h_{-1}
                }
            } else {
                if (tid < 16) {
                    int b = tid;
                    float m[5], zp[5];
                    float M = -3.0e38f;
                    for (int i = 0; i < 5; ++i) {
                        m[i] = aload(&Mpart[i * 16 + b]); zp[i] = aload(&Zpart[i * 16 + b]);
                        M = fmaxf(M, m[i]);
                    }
                    float den = 0.f;
                    for (int i = 0; i < 5; ++i) {
                        float s = __expf(m[i] - M);
                        swL[i * 16 + b] = s;
                        den = fmaf(zp[i], s, den);
                    }
                    invd[b] = 1.f / den;
                }
                __syncthreads();
                for (int idx = tid; idx < 4096; idx += 512) {
                    int b = idx >> 8, k = idx & 255;
                    float v = 0.f;
                    for (int i = 0; i < 5; ++i)
                        v = fmaf(aload(&Cpart[(i * 16 + b) * H_ + k]), swL[i * 16 + b], v);
                    v *= invd[b];
                    vL[b * 512 + k] = v;
                    if (w == b) ws_ctx[((t - 1) * 16 + b) * H_ + k] = v;   // record ctx_{t-1}
                    vL[b * 512 + 256 + k] = aload(&ws_h[((t - 1) * 16 + b) * H_ + k]);
                }
            }
        }
        if (t == T_) break;

        // ---- z = [ctx,h] @ K, gates ----
        if (w < 64) {
            __syncthreads();
            const int wv = tid >> 6, kl = tid & 63, k0 = kl << 3;
            for (int pass = 0; pass < 2; ++pass) {
                const int cs = pass * 8 + wv;       // cs = gate*4 + unit_offset
                const float4 kv0 = *(const float4*)(Kl + cs * 512 + k0);
                const float4 kv1 = *(const float4*)(Kl + cs * 512 + k0 + 4);
                for (int b = 0; b < 16; ++b) {
                    float4 v0 = *(const float4*)(vL + b * 512 + k0);
                    float4 v1 = *(const float4*)(vL + b * 512 + k0 + 4);
                    float acc = v0.x * kv0.x;
                    acc = fmaf(v0.y, kv0.y, acc); acc = fmaf(v0.z, kv0.z, acc);
                    acc = fmaf(v0.w, kv0.w, acc); acc = fmaf(v1.x, kv1.x, acc);
                    acc = fmaf(v1.y, kv1.y, acc); acc = fmaf(v1.z, kv1.z, acc);
                    acc = fmaf(v1.w, kv1.w, acc);
                    for (int off = 32; off; off >>= 1) acc += __shfl_xor(acc, off);
                    if (kl == 0) zscr[cs * 17 + b] = acc;
                }
            }
            __syncthreads();
            if (tid < 64) {                         // gates (keras order i,f,g,o)
                const int gu = tid >> 4, gb = tid & 15;
                const float* zp2 = Zpre + (t * 16 + gb) * H4_;
                float zi = zscr[gu * 17 + gb]        + zp2[ub + gu];
                float zf = zscr[(4 + gu) * 17 + gb]  + zp2[256 + ub + gu];
                float zg = zscr[(8 + gu) * 17 + gb]  + zp2[512 + ub + gu];
                float zo = zscr[(12 + gu) * 17 + gb] + zp2[768 + ub + gu];
                float cn = sigm(zf) * c_state + sigm(zi) * tanhf(zg);
                c_state = cn;
                astore(&ws_h[(t * 16 + gb) * H_ + ub + gu], sigm(zo) * tanhf(cn));
            }
        }
        gbar(bar, 2 * t + 1);

        // ---- phase B: attention partials (all 80 WGs) ----
        {
            const int bw = w & 15, sg = w >> 4;
            if (tid < H_) hA[tid] = aload(&ws_h[(t * 16 + bw) * H_ + tid]);
            __syncthreads();
            if (tid < 320) {                        // 4 lanes per s-row
                const int s = tid >> 2, kq = tid & 3;
                const float* mrow = memw + (bw * S_ + sg * 80 + s) * H_ + (kq << 6);
                const float* ha = hA + (kq << 6);
                float e = 0.f;
                for (int k = 0; k < 64; k += 4) {
                    float4 mm = *(const float4*)(mrow + k);
                    e = fmaf(ha[k], mm.x, e);     e = fmaf(ha[k + 1], mm.y, e);
                    e = fmaf(ha[k + 2], mm.z, e); e = fmaf(ha[k + 3], mm.w, e);
                }
                e += __shfl_xor(e, 1);
                e += __shfl_xor(e, 2);
                if (kq == 0) {
                    if (enc_mask[bw * S_ + sg * 80 + s] == 0) e = NEG_;
                    ws_en[(t * 16 + bw) * S_ + sg * 80 + s] = e;   // masked energy = copy score
                    eL[s] = e;
                }
            }
            __syncthreads();
            if (tid < 64) {
                float m = eL[tid];
                if (tid < 16) m = fmaxf(m, eL[64 + tid]);
                for (int off = 32; off; off >>= 1) m = fmaxf(m, __shfl_down(m, off));
                if (tid == 0) red1[0] = m;
            }
            __syncthreads();
            const float mw = red1[0];
            if (tid < 80) pL[tid] = __expf(eL[tid] - mw);
            __syncthreads();
            if (tid < 64) {
                float zz = pL[tid] + ((tid < 16) ? pL[64 + tid] : 0.f);
                for (int off = 32; off; off >>= 1) zz += __shfl_down(zz, off);
                if (tid == 0) { astore(&Mpart[sg * 16 + bw], mw); astore(&Zpart[sg * 16 + bw], zz); }
            }
            {   // ctx partial: k = tid&255, s-halves of 40 summed across tid>>8
                const int k = tid & 255, half = tid >> 8;
                float acc = 0.f;
                const float* mbase = memw + (bw * S_ + sg * 80) * H_;
                for (int s = half * 40; s < half * 40 + 40; ++s)
                    acc = fmaf(pL[s], mbase[s * H_ + k], acc);
                cL[tid] = acc;
                __syncthreads();
                if (tid < 256) astore(&Cpart[(sg * 16 + bw) * H_ + tid], cL[tid] + cL[tid + 256]);
            }
        }
        gbar(bar, 2 * t + 2);
    }
}

// ---------------- epilogue kernels ----------------

// a[tb] = tanh([h,ctx] @ W_cat + b_cat) -> bf16
__global__ void k_precat(const float* __restrict__ ws_h, const float* __restrict__ ws_ctx,
                         const float* __restrict__ W_cat, const float* __restrict__ b_cat,
                         unsigned short* __restrict__ Abf) {
    __shared__ float u[16][512];
    int base = blockIdx.x * 16;     // 104 blocks (pad rows 1600..1663 -> 0)
    int tid = threadIdx.x;          // 256
    for (int idx = tid; idx < 16 * 512; idx += 256) {
        int r = idx >> 9, k = idx & 511;
        int row = base + r;
        float v = 0.f;
        if (row < 1600) v = (k < 256) ? ws_h[row * H_ + k] : ws_ctx[row * H_ + (k - 256)];
        u[r][k] = v;
    }
    __syncthreads();
    float acc[16];
    float bc = b_cat[tid];
    for (int r = 0; r < 16; ++r) acc[r] = bc;
    for (int k = 0; k < 512; ++k) {
        float wv = W_cat[k * H_ + tid];
        for (int r = 0; r < 16; ++r) acc[r] = fmaf(u[r][k], wv, acc[r]);
    }
    for (int r = 0; r < 16; ++r) {
        int row = base + r;
        float a = (row < 1600) ? tanhf(acc[r]) : 0.f;
        Abf[row * H_ + tid] = f2bf(a);
    }
}

// W_out [256][50000] fp32 -> Bt [51072][256] bf16 (transposed, zero-padded), bias_pad
__global__ void k_convw(const float* __restrict__ Wout, const float* __restrict__ bout,
                        unsigned short* __restrict__ Bt, float* __restrict__ biasp) {
    __shared__ float tile[64][65];
    int bx = blockIdx.x;   // 0..797
    int by = blockIdx.y;   // 0..3
    int tid = threadIdx.x; // 256
    int tr = tid >> 6, tc = tid & 63;
    for (int i = 0; i < 16; ++i) {
        int k = by * 64 + tr + i * 4;
        int n = bx * 64 + tc;
        tile[tr + i * 4][tc] = (n < V_) ? Wout[k * V_ + n] : 0.f;
    }
    __syncthreads();
    for (int i = 0; i < 16; ++i) {
        int nl = tr + i * 4;
        int n = bx * 64 + nl;
        int k = by * 64 + tc;
        Bt[n * 256 + k] = f2bf(tile[tc][nl]);
    }
    if (by == 0 && tid < 64) {
        int n = bx * 64 + tid;
        biasp[n] = (n < V_) ? bout[n] : 0.f;
    }
}

typedef __attribute__((ext_vector_type(8))) __bf16 bf16x8;
typedef __attribute__((ext_vector_type(4))) float f32x4;

// out[b,t,:] = A[tb] @ W_out^T(bf16) + bias   M=1600(pad 1664) N=51072(guard 51000) K=256
__global__ void __launch_bounds__(256) k_gemm(
    const unsigned short* __restrict__ A, const unsigned short* __restrict__ Bt,
    const float* __restrict__ biasp, float* __restrict__ out) {
    __shared__ __align__(16) unsigned short As[128 * 64];
    __shared__ __align__(16) unsigned short Bs[128 * 64];
    const int nb = blockIdx.x, mb = blockIdx.y;
    const int tid = threadIdx.x;
    const int lane = tid & 63, wv = tid >> 6;
    const int wm = wv >> 1, wn = wv & 1;
    const int q = lane >> 4, r16 = lane & 15;
    f32x4 acc[4][4];
    for (int i = 0; i < 4; ++i) for (int j = 0; j < 4; ++j) acc[i][j] = (f32x4)0.f;
    for (int kb = 0; kb < 4; ++kb) {
        for (int i = 0; i < 4; ++i) {   // stage 128x64 A and B tiles, XOR-swizzled rows
            int idx = tid + (i << 8);
            int m = idx >> 3, c = idx & 7;
            int sl = ((c ^ (m & 7)) << 3);
            *(uint4*)(As + (m << 6) + sl) = *(const uint4*)(A + (mb * 128 + m) * 256 + (kb << 6) + (c << 3));
            *(uint4*)(Bs + (m << 6) + sl) = *(const uint4*)(Bt + (nb * 128 + m) * 256 + (kb << 6) + (c << 3));
        }
        __syncthreads();
        for (int k32 = 0; k32 < 2; ++k32) {
            bf16x8 af[4], bfr[4];
            int c = (k32 << 2) + q;
            for (int mt = 0; mt < 4; ++mt) {
                int m = wm * 64 + mt * 16 + r16;
                af[mt] = *(const bf16x8*)(As + (m << 6) + ((c ^ (m & 7)) << 3));
            }
            for (int nt = 0; nt < 4; ++nt) {
                int n = wn * 64 + nt * 16 + r16;
                bfr[nt] = *(const bf16x8*)(Bs + (n << 6) + ((c ^ (n & 7)) << 3));
            }
            for (int mt = 0; mt < 4; ++mt)
                for (int nt = 0; nt < 4; ++nt)
                    acc[mt][nt] = __builtin_amdgcn_mfma_f32_16x16x32_bf16(af[mt], bfr[nt], acc[mt][nt], 0, 0, 0);
        }
        __syncthreads();
    }
    for (int nt = 0; nt < 4; ++nt) {
        int col = nb * 128 + wn * 64 + nt * 16 + r16;
        if (col >= EXTV) continue;
        float bs = biasp[col];
        for (int mt = 0; mt < 4; ++mt) {
            int rbase = mb * 128 + wm * 64 + mt * 16 + (q << 2);
            for (int rg = 0; rg < 4; ++rg) {
                int row = rbase + rg;
                if (row < 1600) {
                    int tt = row >> 4, bb = row & 15;
                    out[(bb * T_ + tt) * EXTV + col] = acc[mt][nt][rg] + bs;
                }
            }
        }
    }
}

// pointer-generator copy scores: per (b,t) scatter-max of masked energy, += into out
__global__ void k_scatter(const int* __restrict__ ext_ids, const float* __restrict__ ws_en,
                          float* __restrict__ out) {
    __shared__ int ids[S_];
    __shared__ float en[S_];
    int r = blockIdx.x;           // t*16+b
    int t = r >> 4, b = r & 15;
    int tid = threadIdx.x;        // 256
    for (int s = tid; s < S_; s += 256) {
        ids[s] = ext_ids[b * S_ + s];
        en[s] = ws_en[r * S_ + s];
    }
    __syncthreads();
    for (int s = tid; s < S_; s += 256) {
        int id = ids[s];
        float mx = en[s];
        int fo = s;
        for (int s2 = 0; s2 < S_; ++s2) {
            if (ids[s2] == id) { mx = fmaxf(mx, en[s2]); if (s2 < fo) fo = s2; }
        }
        if (fo == s && mx >= NEG_ * 0.5f)
            out[(b * T_ + t) * EXTV + id] += mx;
    }
}

// ---------------- launch ----------------

extern "C" void kernel_launch(void* const* d_in, const int* in_sizes, int n_in,
                              void* d_out, int out_size, void* d_ws, size_t ws_size,
                              hipStream_t stream) {
    (void)in_sizes; (void)n_in; (void)out_size; (void)ws_size;
    const int*   trg     = (const int*)d_in[0];
    const int*   ext_ids = (const int*)d_in[1];
    const int*   mask    = (const int*)d_in[2];
    const float* enc     = (const float*)d_in[3];
    const float* init_h  = (const float*)d_in[4];
    const float* init_c  = (const float*)d_in[5];
    const float* emb     = (const float*)d_in[6];
    const float* W_enc   = (const float*)d_in[7];
    const float* b_enc   = (const float*)d_in[8];
    const float* W_red   = (const float*)d_in[9];
    const float* b_red   = (const float*)d_in[10];
    const float* Wx      = (const float*)d_in[11];
    const float* Wh      = (const float*)d_in[12];
    const float* b_lstm  = (const float*)d_in[13];
    const float* W_cat   = (const float*)d_in[14];
    const float* b_cat   = (const float*)d_in[15];
    const float* W_out   = (const float*)d_in[16];
    const float* b_out   = (const float*)d_in[17];
    float* out = (float*)d_out;

    char* p = (char*)d_ws;
    auto alloc = [&](size_t bytes) { char* r = p; p += ((bytes + 255) & ~size_t(255)); return r; };
    float* mem_w = (float*)alloc(1638400u * 4);    // [16][400][256]
    float* Kt    = (float*)alloc(524288u * 4);     // [1024][512]
    float* WtW   = (float*)alloc(131072u * 4);     // [128][1024]
    float* bvec  = (float*)alloc(1024u * 4);
    float* Zpre  = (float*)alloc(1638400u * 4);    // [1600][1024]
    float* Mpart = (float*)alloc(128u * 4);
    float* Zpart = (float*)alloc(128u * 4);
    float* Cpart = (float*)alloc(20480u * 4);      // [5][16][256]
    float* ws_h  = (float*)alloc(409600u * 4);     // [1600][256]
    float* ws_ctx= (float*)alloc(409600u * 4);
    float* ws_en = (float*)alloc(640000u * 4);     // [1600][400]
    unsigned short* Abf = (unsigned short*)alloc(425984u * 2);     // [1664][256] bf16
    unsigned short* Bt  = (unsigned short*)alloc(13074432u * 2);   // [51072][256] bf16
    float* biasp = (float*)alloc(51072u * 4);
    int* bar = (int*)alloc(2048u * 4);             // padded flags + gen

    k_init<<<dim3(1), dim3(256), 0, stream>>>(bar);
    k_mem<<<dim3(400), dim3(256), 0, stream>>>(enc, W_enc, b_enc, mem_w);
    k_prepw<<<dim3(4, 641), dim3(256), 0, stream>>>(W_red, Wx, Wh, b_red, b_lstm, Kt, WtW, bvec);
    k_zpre<<<dim3(100, 4), dim3(256), 0, stream>>>(trg, emb, WtW, bvec, Zpre);

    k_loop<<<dim3(NWG_), dim3(512), 0, stream>>>(Kt, Zpre, init_h, init_c, mem_w, mask,
                                                 Mpart, Zpart, Cpart, ws_h, ws_ctx, ws_en, bar);

    k_precat<<<dim3(104), dim3(256), 0, stream>>>(ws_h, ws_ctx, W_cat, b_cat, Abf);
    k_convw<<<dim3(798, 4), dim3(256), 0, stream>>>(W_out, b_out, Bt, biasp);
    k_gemm<<<dim3(399, 13), dim3(256), 0, stream>>>(Abf, Bt, biasp, out);
    k_scatter<<<dim3(1600), dim3(256), 0, stream>>>(ext_ids, ws_en, out);
}